// Round 14
// baseline (73.565 us; speedup 1.0000x reference)
//
#include <hip/hip_runtime.h>
#include <hip/hip_bf16.h>

typedef __attribute__((ext_vector_type(8))) short s16x8;
typedef __attribute__((ext_vector_type(4))) short s16x4;
typedef __attribute__((ext_vector_type(4))) float fx4;

#define DEVINL __device__ __forceinline__

constexpr int EMBED = 768;
constexpr int HD    = 64;
constexpr int NB    = 16;
constexpr int LEN   = 1024;
constexpr int M_TOT = NB * LEN;   // 16384
constexpr int KVQ   = LEN / 4;    // 256 kv per group in fused attn
constexpr int WELEM = HD * EMBED; // 49152
constexpr int NSTEP = EMBED / 32; // 24

// fp32 -> bf16 RNE via v_cvt_pk_bf16_f32 (2 elems/inst).
DEVINL unsigned pk2(float lo, float hi) {
  __hip_bfloat162 h = __float22bfloat162_rn(float2{lo, hi});
  union { __hip_bfloat162 h; unsigned u; } c; c.h = h;
  return c.u;
}
DEVINL s16x8 cvt8(fx4 a, fx4 b) {
  union { unsigned u[4]; s16x8 v; } r;
  r.u[0] = pk2(a[0], a[1]); r.u[1] = pk2(a[2], a[3]);
  r.u[2] = pk2(b[0], b[1]); r.u[3] = pk2(b[2], b[3]);
  return r.v;
}
DEVINL s16x4 cvt4(float a0, float a1, float a2, float a3) {
  union { unsigned u[2]; s16x4 v; } r;
  r.u[0] = pk2(a0, a1); r.u[1] = pk2(a2, a3);
  return r.v;
}

DEVINL fx4 mfma16(s16x8 a, s16x8 b, fx4 c) {
  return __builtin_amdgcn_mfma_f32_16x16x32_bf16(a, b, c, 0, 0, 0);
}

// ---------------------------------------------------------------------------
// One-shot: convert Wq|Wk|Wv (each 64x768 fp32) to bf16, packed [3][49152].
// ---------------------------------------------------------------------------
__global__ __launch_bounds__(256) void convert_w_kernel(
    const float* __restrict__ a, const float* __restrict__ b,
    const float* __restrict__ c, short* __restrict__ out)
{
  const int gid = blockIdx.x * 256 + threadIdx.x;   // 18432 threads, 8 elem each
  const int seg = gid / (WELEM / 8);
  const int off = (gid % (WELEM / 8)) * 8;
  const float* src = (seg == 0) ? a : (seg == 1) ? b : c;
  fx4 v0 = *reinterpret_cast<const fx4*>(src + off);
  fx4 v1 = *reinterpret_cast<const fx4*>(src + off + 4);
  *reinterpret_cast<s16x8*>(out + (size_t)seg * WELEM + off) = cvt8(v0, v1);
}

// ---------------------------------------------------------------------------
// Round-14 projection: NO LDS, NO barriers, NO DMA. Every LDS-staged variant
// (r6-r13) hit the same 36-46us wall; this sidesteps the mechanism entirely.
// MFMA fragments are loaded per-lane DIRECTLY from global:
//   X (B-op): lane (fr,fg) reads X[m0+w*16+fr][k+fg*8 .. +8)   (32B, own row)
//   W (A-op): lane (fr,fg) reads Wb[ns*16+fr][k+fg*8 .. +8)    (16B, bf16)
// One VMEM instr = 1KB/wave. Explicit double-buffered NAMED register
// prefetch (r2-attn kA/kB pattern, full unroll -> static indices): next
// step's 6-10 loads are issued before current step's MFMAs, so each wave
// keeps 6-10KB in flight; 8 waves/CU -> ~50-80KB/CU outstanding >> the
// ~9KB Little's-law requirement for HBM saturation. Waves never sync ->
// no vmcnt(0) drains anywhere.
// Grid 512 x 256thr: [0,256) Q from dec, [256,512) K+V^T from enc. BM=64,
// wave = m-quarter (16 rows), full N=64, 24 K-steps of 32.
// ---------------------------------------------------------------------------
template <bool ISQ>
DEVINL void proj_body(const float* __restrict__ X,
                      const short* __restrict__ W1, const short* __restrict__ W2,
                      const float* __restrict__ b1, const float* __restrict__ b2,
                      short* __restrict__ O1, short* __restrict__ VT, int m0)
{
  const int t = threadIdx.x, lane = t & 63, w = t >> 6;
  const int fr = lane & 15, fg = lane >> 4;

  // this lane's row bases (element offsets step by 32 per K-step)
  const float* xrow = X + (size_t)(m0 + w * 16 + fr) * EMBED + fg * 8;
  const short* w1f  = W1 + (size_t)fr * EMBED + fg * 8;   // + ns*16*EMBED
  const short* w2f  = W2 ? (W2 + (size_t)fr * EMBED + fg * 8) : nullptr;

  fx4   xbuf[2][2];
  s16x8 w1buf[2][4];
  s16x8 w2buf[2][4];

  auto loadstep = [&](int ke, int pb) {    // ke = element offset (k*32)
    xbuf[pb][0] = *reinterpret_cast<const fx4*>(xrow + ke);
    xbuf[pb][1] = *reinterpret_cast<const fx4*>(xrow + ke + 4);
#pragma unroll
    for (int ns = 0; ns < 4; ++ns) {
      w1buf[pb][ns] = *reinterpret_cast<const s16x8*>(w1f + ns * 16 * EMBED + ke);
      if (!ISQ)
        w2buf[pb][ns] = *reinterpret_cast<const s16x8*>(w2f + ns * 16 * EMBED + ke);
    }
  };

  fx4 acc1[4], acc2[4];
#pragma unroll
  for (int j = 0; j < 4; ++j) {
    acc1[j] = fx4{0.f, 0.f, 0.f, 0.f};
    acc2[j] = fx4{0.f, 0.f, 0.f, 0.f};
  }

  loadstep(0, 0);
#pragma unroll
  for (int k = 0; k < NSTEP; ++k) {
    if (k + 1 < NSTEP) loadstep((k + 1) * 32, (k + 1) & 1);  // issue ahead
    const int pb = k & 1;
    s16x8 xa = cvt8(xbuf[pb][0], xbuf[pb][1]);
#pragma unroll
    for (int ns = 0; ns < 4; ++ns) {
      acc1[ns] = mfma16(w1buf[pb][ns], xa, acc1[ns]);
      if (!ISQ) acc2[ns] = mfma16(w2buf[pb][ns], xa, acc2[ns]);
    }
  }

  // epilogue: D[n][m]: n = ns*16+fg*4+r, m-col = fr; m = m0 + w*16 + fr
  const int m = m0 + w * 16 + fr;
#pragma unroll
  for (int ns = 0; ns < 4; ++ns) {
    const int n0 = ns * 16 + fg * 4;
    fx4 bb = *reinterpret_cast<const fx4*>(b1 + n0);
    *reinterpret_cast<s16x4*>(O1 + (size_t)m * HD + n0) =
        cvt4(acc1[ns][0] + bb[0], acc1[ns][1] + bb[1],
             acc1[ns][2] + bb[2], acc1[ns][3] + bb[3]);
    if (!ISQ) {
      fx4 vb = *reinterpret_cast<const fx4*>(b2 + n0);
      const int bidx = m0 >> 10;              // 64 | 1024: no batch straddle
      const int kvp  = (m0 & 1023) + w * 16 + fr;
#pragma unroll
      for (int r = 0; r < 4; ++r)
        VT[((size_t)(bidx * HD + n0 + r)) * LEN + kvp] =
            (short)pk2(acc2[ns][r] + vb[r], 0.f);
    }
  }
}

__global__ __launch_bounds__(256, 2) void proj_kernel(
    const float* __restrict__ dec, const float* __restrict__ enc,
    const short* __restrict__ wbuf,   // [3][WELEM] bf16: Wq | Wk | Wv
    const float* __restrict__ bq, const float* __restrict__ bk,
    const float* __restrict__ bv,
    short* __restrict__ Qout, short* __restrict__ Kout,
    short* __restrict__ VT)
{
  if (blockIdx.x < 256) {
    proj_body<true>(dec, wbuf, nullptr, bq, nullptr,
                    Qout, nullptr, (int)blockIdx.x * 64);
  } else {
    proj_body<false>(enc, wbuf + WELEM, wbuf + 2 * (size_t)WELEM, bk, bv,
                     Kout, VT, ((int)blockIdx.x - 256) * 64);
  }
}

// ---------------------------------------------------------------------------
// Fused flash attention (unchanged; ~2-3 us). 1024 threads = 16 waves =
// 4 KV-groups x 4 q-waves; K/V LDS-staged per group; lane-local softmax;
// partial combine through LDS overlay.
// ---------------------------------------------------------------------------
__global__ __launch_bounds__(1024, 4) void attn_kernel(
    const short* __restrict__ Q, const short* __restrict__ K,
    const short* __restrict__ VT, float* __restrict__ Out)
{
  __shared__ __align__(16) char smem[110592];
  short (*Kls)[64][72]  = reinterpret_cast<short(*)[64][72]>(smem);
  short (*Vls)[64][72]  = reinterpret_cast<short(*)[64][72]>(smem + 36864);
  short (*Plds)[16][72] = reinterpret_cast<short(*)[16][72]>(smem + 73728);
  float (*HL)[64][68]   = reinterpret_cast<float(*)[64][68]>(smem);
  float2 (*ML)[64]      = reinterpret_cast<float2(*)[64]>(smem + 69632);

  const int t = threadIdx.x, lane = t & 63, w = t >> 6;
  const int g = w >> 2, wl = w & 3;
  const int fr = lane & 15, fg = lane >> 4;
  const int xcd = blockIdx.x & 7;
  const int idx = blockIdx.x >> 3;        // 0..31
  const int b   = xcd + ((idx & 1) << 3);
  const int q0  = (idx >> 1) * 64;
  const int qrow = q0 + wl * 16;

  const short* Qb  = Q  + (size_t)b * LEN * HD;
  const short* Kb  = K  + ((size_t)b * LEN + g * KVQ) * HD;
  const short* VTb = VT + (size_t)b * HD * LEN + g * KVQ;

  s16x8 qa0 = *reinterpret_cast<const s16x8*>(Qb + (size_t)(qrow + fr) * HD + fg * 8);
  s16x8 qa1 = *reinterpret_cast<const s16x8*>(Qb + (size_t)(qrow + fr) * HD + 32 + fg * 8);

  fx4 hacc[4];
#pragma unroll
  for (int c = 0; c < 4; ++c) hacc[c] = fx4{0.f, 0.f, 0.f, 0.f};
  float mrun = -1e30f, lsum = 0.f;
  const float SC = 0.125f * 1.44269504088896340736f;  // 1/sqrt(64) * log2(e)

  const int u = t & 255;
  const int srow = u >> 2;          // 0..63
  const int sch  = (u & 3) * 16;    // short col offset: 0,16,32,48 (32B/lane)

  s16x8 pk0 = *reinterpret_cast<const s16x8*>(Kb + (size_t)srow * HD + sch);
  s16x8 pk1 = *reinterpret_cast<const s16x8*>(Kb + (size_t)srow * HD + sch + 8);
  s16x8 pv0 = *reinterpret_cast<const s16x8*>(VTb + (size_t)srow * LEN + sch);
  s16x8 pv1 = *reinterpret_cast<const s16x8*>(VTb + (size_t)srow * LEN + sch + 8);
  *reinterpret_cast<s16x8*>(&Kls[g][srow][sch])     = pk0;
  *reinterpret_cast<s16x8*>(&Kls[g][srow][sch + 8]) = pk1;
  *reinterpret_cast<s16x8*>(&Vls[g][srow][sch])     = pv0;
  *reinterpret_cast<s16x8*>(&Vls[g][srow][sch + 8]) = pv1;
  __syncthreads();

#pragma unroll
  for (int it = 0; it < KVQ / 64; ++it) {
    if (it + 1 < KVQ / 64) {  // issue next tile's loads before compute
      const int nk = (it + 1) * 64;
      pk0 = *reinterpret_cast<const s16x8*>(Kb + (size_t)(nk + srow) * HD + sch);
      pk1 = *reinterpret_cast<const s16x8*>(Kb + (size_t)(nk + srow) * HD + sch + 8);
      pv0 = *reinterpret_cast<const s16x8*>(VTb + (size_t)srow * LEN + nk + sch);
      pv1 = *reinterpret_cast<const s16x8*>(VTb + (size_t)srow * LEN + nk + sch + 8);
    }
    fx4 sacc[4];
#pragma unroll
    for (int s = 0; s < 4; ++s) {
      s16x8 kf0 = *reinterpret_cast<const s16x8*>(&Kls[g][s * 16 + fr][fg * 8]);
      s16x8 kf1 = *reinterpret_cast<const s16x8*>(&Kls[g][s * 16 + fr][32 + fg * 8]);
      fx4 z = fx4{0.f, 0.f, 0.f, 0.f};
      z = mfma16(kf0, qa0, z);
      sacc[s] = mfma16(kf1, qa1, z);
    }
    float xs[4][4];
    float xm = -1e30f;
#pragma unroll
    for (int s = 0; s < 4; ++s)
#pragma unroll
      for (int r = 0; r < 4; ++r) {
        xs[s][r] = sacc[s][r] * SC;
        xm = fmaxf(xm, xs[s][r]);
      }
    xm = fmaxf(xm, __shfl_xor(xm, 16, 64));
    xm = fmaxf(xm, __shfl_xor(xm, 32, 64));
    const float mn = fmaxf(mrun, xm);
    const float corr = __builtin_amdgcn_exp2f(mrun - mn);
    mrun = mn;
    float ps = 0.f;
#pragma unroll
    for (int s = 0; s < 4; ++s) {
      float p[4];
#pragma unroll
      for (int r = 0; r < 4; ++r) {
        p[r] = __builtin_amdgcn_exp2f(xs[s][r] - mn);
        ps += p[r];
      }
      *reinterpret_cast<s16x4*>(&Plds[w][fr][s * 16 + fg * 4]) =
          cvt4(p[0], p[1], p[2], p[3]);
    }
    ps += __shfl_xor(ps, 16, 64);
    ps += __shfl_xor(ps, 32, 64);
    lsum = lsum * corr + ps;
    __builtin_amdgcn_wave_barrier();
    s16x8 pa0 = *reinterpret_cast<const s16x8*>(&Plds[w][fr][fg * 8]);
    s16x8 pa1 = *reinterpret_cast<const s16x8*>(&Plds[w][fr][32 + fg * 8]);
#pragma unroll
    for (int c = 0; c < 4; ++c) {
      s16x8 vf0 = *reinterpret_cast<const s16x8*>(&Vls[g][c * 16 + fr][fg * 8]);
      s16x8 vf1 = *reinterpret_cast<const s16x8*>(&Vls[g][c * 16 + fr][32 + fg * 8]);
      fx4 h = hacc[c];
#pragma unroll
      for (int r = 0; r < 4; ++r) h[r] *= corr;
      h = mfma16(vf0, pa0, h);
      hacc[c] = mfma16(vf1, pa1, h);
    }
    __syncthreads();  // all waves done reading tile it
    if (it + 1 < KVQ / 64) {
      *reinterpret_cast<s16x8*>(&Kls[g][srow][sch])     = pk0;
      *reinterpret_cast<s16x8*>(&Kls[g][srow][sch + 8]) = pk1;
      *reinterpret_cast<s16x8*>(&Vls[g][srow][sch])     = pv0;
      *reinterpret_cast<s16x8*>(&Vls[g][srow][sch + 8]) = pv1;
    }
    __syncthreads();  // tile it+1 visible
  }
#pragma unroll
  for (int c = 0; c < 4; ++c)
    *reinterpret_cast<fx4*>(&HL[g][wl * 16 + fr][c * 16 + fg * 4]) = hacc[c];
  if (fg == 0) ML[g][wl * 16 + fr] = make_float2(mrun, lsum);
  __syncthreads();
  const int row = t >> 4, d0 = (t & 15) * 4;
  const float2 s0 = ML[0][row], s1 = ML[1][row], s2 = ML[2][row], s3 = ML[3][row];
  const float mm = fmaxf(fmaxf(s0.x, s1.x), fmaxf(s2.x, s3.x));
  const float w0 = __builtin_amdgcn_exp2f(s0.x - mm);
  const float w1 = __builtin_amdgcn_exp2f(s1.x - mm);
  const float w2 = __builtin_amdgcn_exp2f(s2.x - mm);
  const float w3 = __builtin_amdgcn_exp2f(s3.x - mm);
  const float inv = 1.0f / (s0.y * w0 + s1.y * w1 + s2.y * w2 + s3.y * w3);
  fx4 h0 = *reinterpret_cast<const fx4*>(&HL[0][row][d0]);
  fx4 h1 = *reinterpret_cast<const fx4*>(&HL[1][row][d0]);
  fx4 h2 = *reinterpret_cast<const fx4*>(&HL[2][row][d0]);
  fx4 h3 = *reinterpret_cast<const fx4*>(&HL[3][row][d0]);
  fx4 o;
#pragma unroll
  for (int r = 0; r < 4; ++r)
    o[r] = (h0[r] * w0 + h1[r] * w1 + h2[r] * w2 + h3[r] * w3) * inv;
  *reinterpret_cast<fx4*>(Out + ((size_t)b * LEN + q0 + row) * HD + d0) = o;
}

extern "C" void kernel_launch(void* const* d_in, const int* in_sizes, int n_in,
                              void* d_out, int out_size, void* d_ws, size_t ws_size,
                              hipStream_t stream) {
  const float* dec = (const float*)d_in[0];
  const float* enc = (const float*)d_in[1];
  const float* Wq  = (const float*)d_in[2];
  const float* bq  = (const float*)d_in[3];
  const float* Wk  = (const float*)d_in[4];
  const float* bk  = (const float*)d_in[5];
  const float* Wv  = (const float*)d_in[6];
  const float* bv  = (const float*)d_in[7];
  float* out = (float*)d_out;

  short* qws  = (short*)d_ws;                        // [16384,64] bf16
  short* kws  = qws + (size_t)M_TOT * HD;            // [16384,64] bf16
  short* vtws = kws + (size_t)M_TOT * HD;            // [16,64,1024] bf16
  short* wbuf = vtws + (size_t)NB * HD * LEN;        // [3][49152] bf16 weights

  convert_w_kernel<<<(3 * WELEM / 8) / 256, 256, 0, stream>>>(Wq, Wk, Wv, wbuf);
  proj_kernel<<<512, 256, 0, stream>>>(
      dec, enc, wbuf, bq, bk, bv, qws, kws, vtws);
  attn_kernel<<<NB * (LEN / 64), 1024, 0, stream>>>(qws, kws, vtws, out);
}

// Round 15
// 40.727 us; speedup vs baseline: 1.8063x; 1.8063x over previous
//
#include <hip/hip_runtime.h>
#include <hip/hip_bf16.h>

typedef __attribute__((ext_vector_type(8))) short s16x8;
typedef __attribute__((ext_vector_type(4))) short s16x4;
typedef __attribute__((ext_vector_type(4))) float fx4;

#define DEVINL __device__ __forceinline__

constexpr int EMBED = 768;
constexpr int HD    = 64;
constexpr int NB    = 16;
constexpr int LEN   = 1024;
constexpr int M_TOT = NB * LEN;   // 16384
constexpr int KVQ   = LEN / 4;    // 256 kv per group in fused attn
constexpr int WELEM = HD * EMBED; // 49152

// fp32 -> bf16 RNE via v_cvt_pk_bf16_f32 (2 elems/inst).
DEVINL unsigned pk2(float lo, float hi) {
  __hip_bfloat162 h = __float22bfloat162_rn(float2{lo, hi});
  union { __hip_bfloat162 h; unsigned u; } c; c.h = h;
  return c.u;
}
DEVINL s16x8 cvt8(fx4 a, fx4 b) {
  union { unsigned u[4]; s16x8 v; } r;
  r.u[0] = pk2(a[0], a[1]); r.u[1] = pk2(a[2], a[3]);
  r.u[2] = pk2(b[0], b[1]); r.u[3] = pk2(b[2], b[3]);
  return r.v;
}
DEVINL s16x4 cvt4(float a0, float a1, float a2, float a3) {
  union { unsigned u[2]; s16x4 v; } r;
  r.u[0] = pk2(a0, a1); r.u[1] = pk2(a2, a3);
  return r.v;
}

DEVINL fx4 mfma16(s16x8 a, s16x8 b, fx4 c) {
  return __builtin_amdgcn_mfma_f32_16x16x32_bf16(a, b, c, 0, 0, 0);
}

// async global->LDS DMA, 16B/lane; LDS dest = wave-uniform base + lane*16,
// global source = per-lane (enables source-side swizzle, m173 pattern).
DEVINL void gload16(const void* g, void* l) {
  __builtin_amdgcn_global_load_lds(
      (const __attribute__((address_space(1))) void*)g,
      (__attribute__((address_space(3))) void*)l, 16, 0, 0);
}

// ---------------------------------------------------------------------------
// One-shot: convert Wq|Wk|Wv (each 64x768 fp32) to bf16, packed [3][49152].
// ---------------------------------------------------------------------------
__global__ __launch_bounds__(256) void convert_w_kernel(
    const float* __restrict__ a, const float* __restrict__ b,
    const float* __restrict__ c, short* __restrict__ out)
{
  const int gid = blockIdx.x * 256 + threadIdx.x;   // 18432 threads, 8 elem each
  const int seg = gid / (WELEM / 8);
  const int off = (gid % (WELEM / 8)) * 8;
  const float* src = (seg == 0) ? a : (seg == 1) ? b : c;
  fx4 v0 = *reinterpret_cast<const fx4*>(src + off);
  fx4 v1 = *reinterpret_cast<const fx4*>(src + off + 4);
  *reinterpret_cast<s16x8*>(out + (size_t)seg * WELEM + off) = cvt8(v0, v1);
}

// ---------------------------------------------------------------------------
// Round-15 projection. Byte-rate model from r11-r14: dur = staged_bytes /
// rate(waves/CU). This kernel minimizes BOTH terms simultaneously:
//   * BM=128, BK=64, 12 steps -> staged total 135 MB (W re-staging halved
//     vs r11's 168 MB; X = unique 96 MB).
//   * 512-thread blocks (8 waves/CU; r13 had the right bytes but only 4
//     waves/CU -> 3.9 TB/s; r12 showed 16 waves -> 5.8).
//   * r13's PROVEN counted-vmcnt schedule: stage(k) lands while stage(k+1)
//     stays in flight across raw s_barriers; vmcnt never drains to 0 in the
//     main loop. Per wave per step: 4 X-gloads + 1 W1 (+1 W2 KV) -> literal
//     vmcnt(5)/vmcnt(6).
//   * Source-XOR swizzles (dest linear per HW): X rows 256B pitch, key
//     (row&15)<<4 (16 lanes -> 16 distinct 16B slots, 2-way max on read);
//     W rows 128B pitch, key (row&7)<<4.
// Grid 256 (128 Q + 128 KV), LDS 96KB dbuf -> 1 block/CU, 8 waves.
// Wave w owns m-rows [w*16, w*16+16) x full N=64.
// ---------------------------------------------------------------------------
template <bool ISQ>
DEVINL void proj_body(const float* __restrict__ X,
                      const short* __restrict__ W1, const short* __restrict__ W2,
                      const float* __restrict__ b1, const float* __restrict__ b2,
                      short* __restrict__ O1, short* __restrict__ VT,
                      int m0, char* smem)
{
  constexpr int NST   = 12;
  constexpr int BUFSZ = 49152;  // X 32768 + W1 8192 + W2 8192
  const int t = threadIdx.x, lane = t & 63, w = t >> 6;   // w = 0..7
  const int fr = lane & 15, fg = lane >> 4;

  const char* Xg  = (const char*)(X + (size_t)m0 * EMBED);
  const char* W1g = (const char*)W1;
  const char* W2g = (const char*)W2;

  // staging source offsets (constant over steps)
  int xsrc[4];
#pragma unroll
  for (int j = 0; j < 4; ++j) {
    const int rw  = j * 4 + (lane >> 4);       // row within wave's 16
    const int col = (lane & 15) * 16;          // 0..240
    xsrc[j] = (w * 16 + rw) * 3072 + (col ^ (rw << 4));
  }
  const int wrw  = lane >> 3;                  // 0..7
  const int wsrc = (w * 8 + wrw) * 1536 + (((lane & 7) * 16) ^ (wrw << 4));

  auto stage = [&](int k) {
    char* buf = smem + (k & 1) * BUFSZ;
#pragma unroll
    for (int j = 0; j < 4; ++j)
      gload16(Xg + k * 256 + xsrc[j], buf + w * 4096 + j * 1024);
    gload16(W1g + k * 128 + wsrc, buf + 32768 + w * 1024);
    if (!ISQ) gload16(W2g + k * 128 + wsrc, buf + 40960 + w * 1024);
  };

  fx4 acc1[4], acc2[4];
#pragma unroll
  for (int j = 0; j < 4; ++j) {
    acc1[j] = fx4{0.f, 0.f, 0.f, 0.f};
    acc2[j] = fx4{0.f, 0.f, 0.f, 0.f};
  }

  auto compute = [&](int k) {
    const char* cur = smem + (k & 1) * BUFSZ;
    const char* xrb = cur + (w * 16 + fr) * 256;
    const int xk = fr << 4;
#pragma unroll
    for (int ks = 0; ks < 2; ++ks) {
      fx4 xlo = *reinterpret_cast<const fx4*>(xrb + ((ks * 128 + fg * 32) ^ xk));
      fx4 xhi = *reinterpret_cast<const fx4*>(xrb + ((ks * 128 + fg * 32 + 16) ^ xk));
      s16x8 xa = cvt8(xlo, xhi);
#pragma unroll
      for (int ns = 0; ns < 4; ++ns) {
        const int wr = ns * 16 + fr;
        const int wo = wr * 128 + ((ks * 64 + fg * 16) ^ ((fr & 7) << 4));
        s16x8 wf1 = *reinterpret_cast<const s16x8*>(cur + 32768 + wo);
        acc1[ns] = mfma16(wf1, xa, acc1[ns]);
        if (!ISQ) {
          s16x8 wf2 = *reinterpret_cast<const s16x8*>(cur + 40960 + wo);
          acc2[ns] = mfma16(wf2, xa, acc2[ns]);
        }
      }
    }
  };

  stage(0);
  stage(1);
  for (int k = 0; k < NST - 1; ++k) {
    // S(k) landed; S(k+1) (5 or 6 instrs) stays in flight across the barrier
    if (ISQ) asm volatile("s_waitcnt vmcnt(5)" ::: "memory");
    else     asm volatile("s_waitcnt vmcnt(6)" ::: "memory");
    __builtin_amdgcn_s_barrier();
    compute(k);
    __builtin_amdgcn_s_barrier();       // all waves done reading buf[k&1]
    if (k + 2 < NST) stage(k + 2);      // lands during step k+1's compute
  }
  asm volatile("s_waitcnt vmcnt(0)" ::: "memory");
  __builtin_amdgcn_s_barrier();
  compute(NST - 1);

  // epilogue: D[n][m]: n = ns*16+fg*4+r, m-col = fr; m = m0 + w*16 + fr
  const int m = m0 + w * 16 + fr;
#pragma unroll
  for (int ns = 0; ns < 4; ++ns) {
    const int n0 = ns * 16 + fg * 4;
    fx4 bb = *reinterpret_cast<const fx4*>(b1 + n0);
    *reinterpret_cast<s16x4*>(O1 + (size_t)m * HD + n0) =
        cvt4(acc1[ns][0] + bb[0], acc1[ns][1] + bb[1],
             acc1[ns][2] + bb[2], acc1[ns][3] + bb[3]);
    if (!ISQ) {
      fx4 vb = *reinterpret_cast<const fx4*>(b2 + n0);
      const int bidx = m0 >> 10;              // 128 | 1024: no batch straddle
      const int kvp  = (m0 & 1023) + w * 16 + fr;
#pragma unroll
      for (int r = 0; r < 4; ++r)
        VT[((size_t)(bidx * HD + n0 + r)) * LEN + kvp] =
            (short)pk2(acc2[ns][r] + vb[r], 0.f);
    }
  }
}

__global__ __launch_bounds__(512, 1) void proj_kernel(
    const float* __restrict__ dec, const float* __restrict__ enc,
    const short* __restrict__ wbuf,   // [3][WELEM] bf16: Wq | Wk | Wv
    const float* __restrict__ bq, const float* __restrict__ bk,
    const float* __restrict__ bv,
    short* __restrict__ Qout, short* __restrict__ Kout,
    short* __restrict__ VT)
{
  __shared__ __align__(16) char smem[98304];
  if (blockIdx.x < 128) {
    proj_body<true>(dec, wbuf, nullptr, bq, nullptr,
                    Qout, nullptr, (int)blockIdx.x * 128, smem);
  } else {
    proj_body<false>(enc, wbuf + WELEM, wbuf + 2 * (size_t)WELEM, bk, bv,
                     Kout, VT, ((int)blockIdx.x - 128) * 128, smem);
  }
}

// ---------------------------------------------------------------------------
// Fused flash attention (unchanged; ~3.5 us). 1024 threads = 16 waves =
// 4 KV-groups x 4 q-waves; K/V LDS-staged per group; lane-local softmax;
// partial combine through LDS overlay.
// ---------------------------------------------------------------------------
__global__ __launch_bounds__(1024, 4) void attn_kernel(
    const short* __restrict__ Q, const short* __restrict__ K,
    const short* __restrict__ VT, float* __restrict__ Out)
{
  __shared__ __align__(16) char smem[110592];
  short (*Kls)[64][72]  = reinterpret_cast<short(*)[64][72]>(smem);
  short (*Vls)[64][72]  = reinterpret_cast<short(*)[64][72]>(smem + 36864);
  short (*Plds)[16][72] = reinterpret_cast<short(*)[16][72]>(smem + 73728);
  float (*HL)[64][68]   = reinterpret_cast<float(*)[64][68]>(smem);
  float2 (*ML)[64]      = reinterpret_cast<float2(*)[64]>(smem + 69632);

  const int t = threadIdx.x, lane = t & 63, w = t >> 6;
  const int g = w >> 2, wl = w & 3;
  const int fr = lane & 15, fg = lane >> 4;
  const int xcd = blockIdx.x & 7;
  const int idx = blockIdx.x >> 3;        // 0..31
  const int b   = xcd + ((idx & 1) << 3);
  const int q0  = (idx >> 1) * 64;
  const int qrow = q0 + wl * 16;

  const short* Qb  = Q  + (size_t)b * LEN * HD;
  const short* Kb  = K  + ((size_t)b * LEN + g * KVQ) * HD;
  const short* VTb = VT + (size_t)b * HD * LEN + g * KVQ;

  s16x8 qa0 = *reinterpret_cast<const s16x8*>(Qb + (size_t)(qrow + fr) * HD + fg * 8);
  s16x8 qa1 = *reinterpret_cast<const s16x8*>(Qb + (size_t)(qrow + fr) * HD + 32 + fg * 8);

  fx4 hacc[4];
#pragma unroll
  for (int c = 0; c < 4; ++c) hacc[c] = fx4{0.f, 0.f, 0.f, 0.f};
  float mrun = -1e30f, lsum = 0.f;
  const float SC = 0.125f * 1.44269504088896340736f;  // 1/sqrt(64) * log2(e)

  const int u = t & 255;
  const int srow = u >> 2;          // 0..63
  const int sch  = (u & 3) * 16;    // short col offset: 0,16,32,48 (32B/lane)

  s16x8 pk0 = *reinterpret_cast<const s16x8*>(Kb + (size_t)srow * HD + sch);
  s16x8 pk1 = *reinterpret_cast<const s16x8*>(Kb + (size_t)srow * HD + sch + 8);
  s16x8 pv0 = *reinterpret_cast<const s16x8*>(VTb + (size_t)srow * LEN + sch);
  s16x8 pv1 = *reinterpret_cast<const s16x8*>(VTb + (size_t)srow * LEN + sch + 8);
  *reinterpret_cast<s16x8*>(&Kls[g][srow][sch])     = pk0;
  *reinterpret_cast<s16x8*>(&Kls[g][srow][sch + 8]) = pk1;
  *reinterpret_cast<s16x8*>(&Vls[g][srow][sch])     = pv0;
  *reinterpret_cast<s16x8*>(&Vls[g][srow][sch + 8]) = pv1;
  __syncthreads();

#pragma unroll
  for (int it = 0; it < KVQ / 64; ++it) {
    if (it + 1 < KVQ / 64) {  // issue next tile's loads before compute
      const int nk = (it + 1) * 64;
      pk0 = *reinterpret_cast<const s16x8*>(Kb + (size_t)(nk + srow) * HD + sch);
      pk1 = *reinterpret_cast<const s16x8*>(Kb + (size_t)(nk + srow) * HD + sch + 8);
      pv0 = *reinterpret_cast<const s16x8*>(VTb + (size_t)srow * LEN + nk + sch);
      pv1 = *reinterpret_cast<const s16x8*>(VTb + (size_t)srow * LEN + nk + sch + 8);
    }
    fx4 sacc[4];
#pragma unroll
    for (int s = 0; s < 4; ++s) {
      s16x8 kf0 = *reinterpret_cast<const s16x8*>(&Kls[g][s * 16 + fr][fg * 8]);
      s16x8 kf1 = *reinterpret_cast<const s16x8*>(&Kls[g][s * 16 + fr][32 + fg * 8]);
      fx4 z = fx4{0.f, 0.f, 0.f, 0.f};
      z = mfma16(kf0, qa0, z);
      sacc[s] = mfma16(kf1, qa1, z);
    }
    float xs[4][4];
    float xm = -1e30f;
#pragma unroll
    for (int s = 0; s < 4; ++s)
#pragma unroll
      for (int r = 0; r < 4; ++r) {
        xs[s][r] = sacc[s][r] * SC;
        xm = fmaxf(xm, xs[s][r]);
      }
    xm = fmaxf(xm, __shfl_xor(xm, 16, 64));
    xm = fmaxf(xm, __shfl_xor(xm, 32, 64));
    const float mn = fmaxf(mrun, xm);
    const float corr = __builtin_amdgcn_exp2f(mrun - mn);
    mrun = mn;
    float ps = 0.f;
#pragma unroll
    for (int s = 0; s < 4; ++s) {
      float p[4];
#pragma unroll
      for (int r = 0; r < 4; ++r) {
        p[r] = __builtin_amdgcn_exp2f(xs[s][r] - mn);
        ps += p[r];
      }
      *reinterpret_cast<s16x4*>(&Plds[w][fr][s * 16 + fg * 4]) =
          cvt4(p[0], p[1], p[2], p[3]);
    }
    ps += __shfl_xor(ps, 16, 64);
    ps += __shfl_xor(ps, 32, 64);
    lsum = lsum * corr + ps;
    __builtin_amdgcn_wave_barrier();
    s16x8 pa0 = *reinterpret_cast<const s16x8*>(&Plds[w][fr][fg * 8]);
    s16x8 pa1 = *reinterpret_cast<const s16x8*>(&Plds[w][fr][32 + fg * 8]);
#pragma unroll
    for (int c = 0; c < 4; ++c) {
      s16x8 vf0 = *reinterpret_cast<const s16x8*>(&Vls[g][c * 16 + fr][fg * 8]);
      s16x8 vf1 = *reinterpret_cast<const s16x8*>(&Vls[g][c * 16 + fr][32 + fg * 8]);
      fx4 h = hacc[c];
#pragma unroll
      for (int r = 0; r < 4; ++r) h[r] *= corr;
      h = mfma16(vf0, pa0, h);
      hacc[c] = mfma16(vf1, pa1, h);
    }
    __syncthreads();  // all waves done reading tile it
    if (it + 1 < KVQ / 64) {
      *reinterpret_cast<s16x8*>(&Kls[g][srow][sch])     = pk0;
      *reinterpret_cast<s16x8*>(&Kls[g][srow][sch + 8]) = pk1;
      *reinterpret_cast<s16x8*>(&Vls[g][srow][sch])     = pv0;
      *reinterpret_cast<s16x8*>(&Vls[g][srow][sch + 8]) = pv1;
    }
    __syncthreads();  // tile it+1 visible
  }
#pragma unroll
  for (int c = 0; c < 4; ++c)
    *reinterpret_cast<fx4*>(&HL[g][wl * 16 + fr][c * 16 + fg * 4]) = hacc[c];
  if (fg == 0) ML[g][wl * 16 + fr] = make_float2(mrun, lsum);
  __syncthreads();
  const int row = t >> 4, d0 = (t & 15) * 4;
  const float2 s0 = ML[0][row], s1 = ML[1][row], s2 = ML[2][row], s3 = ML[3][row];
  const float mm = fmaxf(fmaxf(s0.x, s1.x), fmaxf(s2.x, s3.x));
  const float w0 = __builtin_amdgcn_exp2f(s0.x - mm);
  const float w1 = __builtin_amdgcn_exp2f(s1.x - mm);
  const float w2 = __builtin_amdgcn_exp2f(s2.x - mm);
  const float w3 = __builtin_amdgcn_exp2f(s3.x - mm);
  const float inv = 1.0f / (s0.y * w0 + s1.y * w1 + s2.y * w2 + s3.y * w3);
  fx4 h0 = *reinterpret_cast<const fx4*>(&HL[0][row][d0]);
  fx4 h1 = *reinterpret_cast<const fx4*>(&HL[1][row][d0]);
  fx4 h2 = *reinterpret_cast<const fx4*>(&HL[2][row][d0]);
  fx4 h3 = *reinterpret_cast<const fx4*>(&HL[3][row][d0]);
  fx4 o;
#pragma unroll
  for (int r = 0; r < 4; ++r)
    o[r] = (h0[r] * w0 + h1[r] * w1 + h2[r] * w2 + h3[r] * w3) * inv;
  *reinterpret_cast<fx4*>(Out + ((size_t)b * LEN + q0 + row) * HD + d0) = o;
}

extern "C" void kernel_launch(void* const* d_in, const int* in_sizes, int n_in,
                              void* d_out, int out_size, void* d_ws, size_t ws_size,
                              hipStream_t stream) {
  const float* dec = (const float*)d_in[0];
  const float* enc = (const float*)d_in[1];
  const float* Wq  = (const float*)d_in[2];
  const float* bq  = (const float*)d_in[3];
  const float* Wk  = (const float*)d_in[4];
  const float* bk  = (const float*)d_in[5];
  const float* Wv  = (const float*)d_in[6];
  const float* bv  = (const float*)d_in[7];
  float* out = (float*)d_out;

  short* qws  = (short*)d_ws;                        // [16384,64] bf16
  short* kws  = qws + (size_t)M_TOT * HD;            // [16384,64] bf16
  short* vtws = kws + (size_t)M_TOT * HD;            // [16,64,1024] bf16
  short* wbuf = vtws + (size_t)NB * HD * LEN;        // [3][49152] bf16 weights

  convert_w_kernel<<<(3 * WELEM / 8) / 256, 256, 0, stream>>>(Wq, Wk, Wv, wbuf);
  proj_kernel<<<256, 512, 0, stream>>>(
      dec, enc, wbuf, bq, bk, bv, qws, kws, vtws);
  attn_kernel<<<NB * (LEN / 64), 1024, 0, stream>>>(qws, kws, vtws, out);
}